// Round 11
// baseline (289.854 us; speedup 1.0000x reference)
//
#include <hip/hip_runtime.h>

// TwoStageRegressionLoss: fused BCE + duration-aware focal smooth-L1 mean
// reduction over N = 2048*16384 fp32 (4 input arrays, 537 MB read).
// History: R1 libm logf VALU-bound 77%. R2 hw __log2f -> 101us anchor.
// R3/R4 VGPR pipelines -> compiler sank loads. R5 asm "=v" loads -> fault.
// R6 stream-split -> neutral. R7 global_load_lds 3-slot ring + counted
// vmcnt(2) -> 97.45us (best). R8 deeper ring -> occ collapse, FAIL. R9
// issue-early -> FAIL. R10 revert R7 -> 101.4us => noise band +-4%; loop
// levers exhausted at ~5.3 TB/s effective (84% of 6.29 TB/s ceiling).
// R11: kill the serial final_kernel launch - fold the cross-block reduce
// into partial_kernel via deterministic q24 int64 atomics (R4-validated
// mechanism) + last-block finalize. Main loop untouched R7.

constexpr int BLOCK = 256;
constexpr int HGRID = 2048;        // blocks per loss half
constexpr int GRID  = 2 * HGRID;
constexpr int BUFS  = 3;           // LDS ring slots (2 sets in flight + 1 consuming)
constexpr double SCALE = 16777216.0;   // 2^24 fixed-point quantum

typedef float f32x4 __attribute__((ext_vector_type(4)));

// HW async DMA: lane l of the wave writes 16B to lds_base + l*16.
// gptr is PER-LANE; lds base must be wave-uniform (guide §5, m97/m104).
__device__ __forceinline__ void stage16(const float* g, void* l) {
    __builtin_amdgcn_global_load_lds(
        (const __attribute__((address_space(1))) void*)g,
        (__attribute__((address_space(3))) void*)l,
        16, 0, 0);
}

#define WAITV(N) do { \
    asm volatile("s_waitcnt vmcnt(" #N ")" ::: "memory"); \
    __builtin_amdgcn_sched_barrier(0); \
} while (0)

__device__ __forceinline__ void bce_elem(float pv, float tv, float& acc) {
    // BCE in log2 domain: clamp(-100) in ln == clamp(-100/ln2) in log2.
    constexpr float CLAMP2 = -144.26950408889634f;
    float pc = fminf(fmaxf(pv, 0.0f), 1.0f);
    float tc = fminf(fmaxf(tv, 0.0f), 1.0f);
    float lp  = fmaxf(__log2f(pc),        CLAMP2);  // v_log_f32; log2(0)=-inf -> clamp
    float l1p = fmaxf(__log2f(1.0f - pc), CLAMP2);
    acc -= l1p + tc * (lp - l1p);   // == tc*lp + (1-tc)*l1p; *ln2 at finalize
}

__device__ __forceinline__ void focal_elem(float qv, float sv, float& acc) {
    // duration-aware focal smooth-L1 (alpha=0.25 applied at finalize)
    float d = fabsf(qv - sv);
    float f = fminf(d + d, 1.0f);                     // clip(d/0.5, 0, 1)
    float base = (d < 0.5f) ? (d * d) : (d - 0.25f);  // smooth L1, beta=0.5
    // class weight: round-half-even (jnp.round), clamp [0,3], table {1,4,3,2}
    float r = fminf(fmaxf(__builtin_rintf(sv), 0.0f), 3.0f);
    float w = (r == 0.0f) ? 1.0f : (r == 1.0f) ? 4.0f : (r == 2.0f) ? 3.0f : 2.0f;
    acc += (f * f) * base * w;
}

template <bool IS_BCE>
__device__ __forceinline__ void accum4(const f32x4& p, const f32x4& t,
                                       float& a0, float& a1) {
    if (IS_BCE) {
        bce_elem(p[0], t[0], a0); bce_elem(p[1], t[1], a1);
        bce_elem(p[2], t[2], a0); bce_elem(p[3], t[3], a1);
    } else {
        focal_elem(p[0], t[0], a0); focal_elem(p[1], t[1], a1);
        focal_elem(p[2], t[2], a0); focal_elem(p[3], t[3], a1);
    }
}

template <bool IS_BCE>
__device__ __forceinline__ void run_half(
    const f32x4* __restrict__ P, const f32x4* __restrict__ T,
    f32x4* smem, int vb, int n4, int n, float& a0, float& a1)
{
    const int tid    = (int)threadIdx.x;
    const int wid    = tid >> 6;
    const int stride = HGRID * BLOCK;           // in float4 units
    const int base   = vb * BLOCK + tid;
    const int iters  = n4 / stride;

    if ((n4 % stride) == 0 && iters >= BUFS) {
        // LDS layout: slot s, stream c -> smem[(s*2+c)*BLOCK + tid]
        // wave-uniform stage base: + wid*64 (HW adds lane*16B)
        // prologue: stage sets 0,1 (4 loads in flight)
        #pragma unroll
        for (int d = 0; d < 2; ++d) {
            stage16((const float*)(P + base + (long)d * stride),
                    (void*)(smem + (d * 2 + 0) * BLOCK + wid * 64));
            stage16((const float*)(T + base + (long)d * stride),
                    (void*)(smem + (d * 2 + 1) * BLOCK + wid * 64));
        }
        for (int it = 0; it < iters; ++it) {
            const int slot = it % BUFS;
            if (it < iters - 1) WAITV(2);    // set `it` done; set it+1 stays in flight
            else                WAITV(0);    // final drain
            // stage set it+2 into slot (it+2)%BUFS == (it-1)%BUFS, which was
            // consumed (ds_read completed) at iteration it-1 -> no alias hazard.
            if (it + 2 < iters) {
                const int s2 = (it + 2) % BUFS;
                stage16((const float*)(P + base + (long)(it + 2) * stride),
                        (void*)(smem + (s2 * 2 + 0) * BLOCK + wid * 64));
                stage16((const float*)(T + base + (long)(it + 2) * stride),
                        (void*)(smem + (s2 * 2 + 1) * BLOCK + wid * 64));
            }
            __builtin_amdgcn_sched_barrier(0);
            f32x4 p = smem[(slot * 2 + 0) * BLOCK + tid];   // ds_read_b128
            f32x4 t = smem[(slot * 2 + 1) * BLOCK + tid];
            accum4<IS_BCE>(p, t, a0, a1);
        }
    } else {
        // generic fallback (R6 structure)
        for (int i = base; i < n4; i += stride) {
            f32x4 p = P[i];
            f32x4 t = T[i];
            accum4<IS_BCE>(p, t, a0, a1);
        }
        if (vb == 0) {  // scalar tail
            const float* Pf = (const float*)P;
            const float* Tf = (const float*)T;
            for (int k = n4 * 4 + tid; k < n; k += BLOCK) {
                if (IS_BCE) bce_elem(Pf[k], Tf[k], a0);
                else        focal_elem(Pf[k], Tf[k], a0);
            }
        }
    }
}

__global__ __launch_bounds__(BLOCK) void partial_kernel(
    const f32x4* __restrict__ bp4, const f32x4* __restrict__ rp4,
    const f32x4* __restrict__ bt4, const f32x4* __restrict__ rt4,
    unsigned long long* __restrict__ ws,   // [0]=sumB q24, [1]=sumR q24, [2]=counter
    float* __restrict__ out, int n4, int n, double invN)
{
    __shared__ f32x4 smem[BUFS * 2 * BLOCK];   // 24 KB -> 6 blocks/CU
    float a0 = 0.0f, a1 = 0.0f;
    const bool isB = (blockIdx.x < (unsigned)HGRID);
    const int  vb  = isB ? blockIdx.x : blockIdx.x - HGRID;

    if (isB) run_half<true >(bp4, bt4, smem, vb, n4, n, a0, a1);
    else     run_half<false>(rp4, rt4, smem, vb, n4, n, a0, a1);

    float acc = a0 + a1;
    // wave-64 reduce
    #pragma unroll
    for (int off = 32; off > 0; off >>= 1)
        acc += __shfl_down(acc, off, 64);
    __shared__ float sA[BLOCK / 64];
    const int lane = threadIdx.x & 63;
    const int wid  = threadIdx.x >> 6;
    if (lane == 0) sA[wid] = acc;
    __syncthreads();
    if (threadIdx.x == 0) {
        float v = 0.0f;
        #pragma unroll
        for (int w = 0; w < BLOCK / 64; ++w) v += sA[w];
        // deterministic q24 fixed-point reduce (int64 adds associative).
        // BCE block sums scaled log2->ln here; focal by alpha=0.25 at finalize.
        double scaled = isB ? ((double)v * 0.6931471805599453 * SCALE)
                            : ((double)v * SCALE);
        atomicAdd(&ws[isB ? 0 : 1],
                  (unsigned long long)(long long)llrint(scaled));
        __threadfence();                        // sum visible before counter bump
        unsigned long long prev = atomicAdd(&ws[2], 1ULL);
        if (prev == (unsigned long long)(GRID - 1)) {   // last block finalizes
            unsigned long long tb = atomicAdd(&ws[0], 0ULL);  // device-scope reads
            unsigned long long tr = atomicAdd(&ws[1], 0ULL);
            double bm = (double)(long long)tb / SCALE * invN;
            double rm = (double)(long long)tr / SCALE * invN * 0.25;  // alpha
            out[0] = (float)(bm + rm);  // total (BREAK_W = REG_W = 1)
            out[1] = (float)bm;         // break_loss
            out[2] = (float)rm;         // regression_loss
        }
    }
}

extern "C" void kernel_launch(void* const* d_in, const int* in_sizes, int n_in,
                              void* d_out, int out_size, void* d_ws, size_t ws_size,
                              hipStream_t stream) {
    // setup_inputs() order: break_predictions, regression_predictions,
    //                       break_targets, regression_targets  (all fp32)
    const float* bp = (const float*)d_in[0];
    const float* rp = (const float*)d_in[1];
    const float* bt = (const float*)d_in[2];
    const float* rt = (const float*)d_in[3];
    const int n  = in_sizes[0];
    const int n4 = n / 4;
    unsigned long long* ws = (unsigned long long*)d_ws;

    // ws poisoned 0xAA once, never re-poisoned -> zero the 3 counters per call.
    // hipMemcpyAsync/hipMemsetAsync are graph-capture-safe.
    hipMemsetAsync(ws, 0, 3 * sizeof(unsigned long long), stream);
    partial_kernel<<<GRID, BLOCK, 0, stream>>>(
        (const f32x4*)bp, (const f32x4*)rp, (const f32x4*)bt, (const f32x4*)rt,
        ws, (float*)d_out, n4, n, 1.0 / (double)n);
}

// Round 12
// 100.856 us; speedup vs baseline: 2.8739x; 2.8739x over previous
//
#include <hip/hip_runtime.h>

// TwoStageRegressionLoss: fused BCE + duration-aware focal smooth-L1 mean
// reduction over N = 2048*16384 fp32 (4 input arrays, 537 MB read).
// History: R1 libm logf VALU-bound 77%. R2 hw __log2f -> 101us anchor.
// R3/R4 VGPR pipelines -> compiler sank loads. R5 asm "=v" loads -> fault.
// R6 stream-split -> neutral. R7 global_load_lds 3-slot ring + counted
// vmcnt(2) -> 97.45us (best). R8 deeper ring -> occ collapse. R9
// issue-early -> worse. R10 revert R7 -> 101.4us (noise band +-4%).
// R11 atomic+threadfence finalize fold -> 290us CATASTROPHIC (replicates
// R4): device-scope fence in the hot kernel serializes the read stream.
// R12: revert to the two-kernel R7 form - the measured optimum. Effective
// 5.3-5.5 TB/s = 84-87% of the 6.29 TB/s copy ceiling => streaming roofline.

constexpr int BLOCK = 256;
constexpr int HGRID = 2048;        // blocks per loss half
constexpr int GRID  = 2 * HGRID;
constexpr int BUFS  = 3;           // LDS ring slots (2 sets in flight + 1 consuming)

typedef float f32x4 __attribute__((ext_vector_type(4)));

// HW async DMA: lane l of the wave writes 16B to lds_base + l*16.
// gptr is PER-LANE; lds base must be wave-uniform (guide §5, m97/m104).
__device__ __forceinline__ void stage16(const float* g, void* l) {
    __builtin_amdgcn_global_load_lds(
        (const __attribute__((address_space(1))) void*)g,
        (__attribute__((address_space(3))) void*)l,
        16, 0, 0);
}

#define WAITV(N) do { \
    asm volatile("s_waitcnt vmcnt(" #N ")" ::: "memory"); \
    __builtin_amdgcn_sched_barrier(0); \
} while (0)

__device__ __forceinline__ void bce_elem(float pv, float tv, float& acc) {
    // BCE in log2 domain: clamp(-100) in ln == clamp(-100/ln2) in log2.
    constexpr float CLAMP2 = -144.26950408889634f;
    float pc = fminf(fmaxf(pv, 0.0f), 1.0f);
    float tc = fminf(fmaxf(tv, 0.0f), 1.0f);
    float lp  = fmaxf(__log2f(pc),        CLAMP2);  // v_log_f32; log2(0)=-inf -> clamp
    float l1p = fmaxf(__log2f(1.0f - pc), CLAMP2);
    acc -= l1p + tc * (lp - l1p);   // == tc*lp + (1-tc)*l1p; *ln2 in final_kernel
}

__device__ __forceinline__ void focal_elem(float qv, float sv, float& acc) {
    // duration-aware focal smooth-L1 (alpha=0.25 applied in final_kernel)
    float d = fabsf(qv - sv);
    float f = fminf(d + d, 1.0f);                     // clip(d/0.5, 0, 1)
    float base = (d < 0.5f) ? (d * d) : (d - 0.25f);  // smooth L1, beta=0.5
    // class weight: round-half-even (jnp.round), clamp [0,3], table {1,4,3,2}
    float r = fminf(fmaxf(__builtin_rintf(sv), 0.0f), 3.0f);
    float w = (r == 0.0f) ? 1.0f : (r == 1.0f) ? 4.0f : (r == 2.0f) ? 3.0f : 2.0f;
    acc += (f * f) * base * w;
}

template <bool IS_BCE>
__device__ __forceinline__ void accum4(const f32x4& p, const f32x4& t,
                                       float& a0, float& a1) {
    if (IS_BCE) {
        bce_elem(p[0], t[0], a0); bce_elem(p[1], t[1], a1);
        bce_elem(p[2], t[2], a0); bce_elem(p[3], t[3], a1);
    } else {
        focal_elem(p[0], t[0], a0); focal_elem(p[1], t[1], a1);
        focal_elem(p[2], t[2], a0); focal_elem(p[3], t[3], a1);
    }
}

template <bool IS_BCE>
__device__ __forceinline__ void run_half(
    const f32x4* __restrict__ P, const f32x4* __restrict__ T,
    f32x4* smem, int vb, int n4, int n, float& a0, float& a1)
{
    const int tid    = (int)threadIdx.x;
    const int wid    = tid >> 6;
    const int stride = HGRID * BLOCK;           // in float4 units
    const int base   = vb * BLOCK + tid;
    const int iters  = n4 / stride;

    if ((n4 % stride) == 0 && iters >= BUFS) {
        // LDS layout: slot s, stream c -> smem[(s*2+c)*BLOCK + tid]
        // wave-uniform stage base: + wid*64 (HW adds lane*16B)
        // prologue: stage sets 0,1 (4 loads in flight)
        #pragma unroll
        for (int d = 0; d < 2; ++d) {
            stage16((const float*)(P + base + (long)d * stride),
                    (void*)(smem + (d * 2 + 0) * BLOCK + wid * 64));
            stage16((const float*)(T + base + (long)d * stride),
                    (void*)(smem + (d * 2 + 1) * BLOCK + wid * 64));
        }
        for (int it = 0; it < iters; ++it) {
            const int slot = it % BUFS;
            if (it < iters - 1) WAITV(2);    // set `it` done; set it+1 stays in flight
            else                WAITV(0);    // final drain
            // stage set it+2 into slot (it+2)%BUFS == (it-1)%BUFS, which was
            // consumed (ds_read completed) at iteration it-1 -> no alias hazard.
            if (it + 2 < iters) {
                const int s2 = (it + 2) % BUFS;
                stage16((const float*)(P + base + (long)(it + 2) * stride),
                        (void*)(smem + (s2 * 2 + 0) * BLOCK + wid * 64));
                stage16((const float*)(T + base + (long)(it + 2) * stride),
                        (void*)(smem + (s2 * 2 + 1) * BLOCK + wid * 64));
            }
            __builtin_amdgcn_sched_barrier(0);
            f32x4 p = smem[(slot * 2 + 0) * BLOCK + tid];   // ds_read_b128
            f32x4 t = smem[(slot * 2 + 1) * BLOCK + tid];
            accum4<IS_BCE>(p, t, a0, a1);
        }
    } else {
        // generic fallback (R6 structure)
        for (int i = base; i < n4; i += stride) {
            f32x4 p = P[i];
            f32x4 t = T[i];
            accum4<IS_BCE>(p, t, a0, a1);
        }
        if (vb == 0) {  // scalar tail
            const float* Pf = (const float*)P;
            const float* Tf = (const float*)T;
            for (int k = n4 * 4 + tid; k < n; k += BLOCK) {
                if (IS_BCE) bce_elem(Pf[k], Tf[k], a0);
                else        focal_elem(Pf[k], Tf[k], a0);
            }
        }
    }
}

__global__ __launch_bounds__(BLOCK) void partial_kernel(
    const f32x4* __restrict__ bp4, const f32x4* __restrict__ rp4,
    const f32x4* __restrict__ bt4, const f32x4* __restrict__ rt4,
    float* __restrict__ partials, int n4, int n)
{
    __shared__ f32x4 smem[BUFS * 2 * BLOCK];   // 24 KB -> 6 blocks/CU
    float a0 = 0.0f, a1 = 0.0f;
    const bool isB = (blockIdx.x < (unsigned)HGRID);
    const int  vb  = isB ? blockIdx.x : blockIdx.x - HGRID;

    if (isB) run_half<true >(bp4, bt4, smem, vb, n4, n, a0, a1);
    else     run_half<false>(rp4, rt4, smem, vb, n4, n, a0, a1);

    float acc = a0 + a1;
    // wave-64 reduce
    #pragma unroll
    for (int off = 32; off > 0; off >>= 1)
        acc += __shfl_down(acc, off, 64);
    __shared__ float sA[BLOCK / 64];
    const int lane = threadIdx.x & 63;
    const int wid  = threadIdx.x >> 6;
    if (lane == 0) sA[wid] = acc;
    __syncthreads();
    if (threadIdx.x == 0) {
        float v = 0.0f;
        #pragma unroll
        for (int w = 0; w < BLOCK / 64; ++w) v += sA[w];
        partials[blockIdx.x] = v;   // [0..HGRID) BCE sums, [HGRID..GRID) focal sums
    }
}

__global__ __launch_bounds__(BLOCK) void final_kernel(
    const float* __restrict__ partials, float* __restrict__ out, double invN)
{
    double accB = 0.0, accR = 0.0;
    for (int i = threadIdx.x; i < HGRID; i += BLOCK) {
        accB += (double)partials[i];
        accR += (double)partials[HGRID + i];
    }
    #pragma unroll
    for (int off = 32; off > 0; off >>= 1) {
        accB += __shfl_down(accB, off, 64);
        accR += __shfl_down(accR, off, 64);
    }
    __shared__ double dB[BLOCK / 64], dR[BLOCK / 64];
    const int lane = threadIdx.x & 63;
    const int wid  = threadIdx.x >> 6;
    if (lane == 0) { dB[wid] = accB; dR[wid] = accR; }
    __syncthreads();
    if (threadIdx.x == 0) {
        double b = 0.0, r = 0.0;
        #pragma unroll
        for (int w = 0; w < BLOCK / 64; ++w) { b += dB[w]; r += dR[w]; }
        const double bm = b * 0.6931471805599453 * invN;  // log2 -> ln
        const double rm = r * 0.25 * invN;                // alpha
        out[0] = (float)(bm + rm);  // total (BREAK_W = REG_W = 1)
        out[1] = (float)bm;         // break_loss
        out[2] = (float)rm;         // regression_loss
    }
}

extern "C" void kernel_launch(void* const* d_in, const int* in_sizes, int n_in,
                              void* d_out, int out_size, void* d_ws, size_t ws_size,
                              hipStream_t stream) {
    // setup_inputs() order: break_predictions, regression_predictions,
    //                       break_targets, regression_targets  (all fp32)
    const float* bp = (const float*)d_in[0];
    const float* rp = (const float*)d_in[1];
    const float* bt = (const float*)d_in[2];
    const float* rt = (const float*)d_in[3];
    const int n  = in_sizes[0];
    const int n4 = n / 4;
    float* partials = (float*)d_ws;   // GRID floats = 16 KB scratch

    partial_kernel<<<GRID, BLOCK, 0, stream>>>(
        (const f32x4*)bp, (const f32x4*)rp, (const f32x4*)bt, (const f32x4*)rt,
        partials, n4, n);
    final_kernel<<<1, BLOCK, 0, stream>>>(partials, (float*)d_out, 1.0 / (double)n);
}